// Round 18
// baseline (169.514 us; speedup 1.0000x reference)
//
#include <hip/hip_runtime.h>
#include <hip/hip_bf16.h>
#include <math.h>

#define DIM   384
#define HEADS 8
#define HD    48
#define HH    96
#define WW    96
#define NPIX  9216
#define OC3   1152
#define NCH   36      // gram n-chunks (36*256 = 9216)
#define NB    4

typedef _Float16 f16x8 __attribute__((ext_vector_type(8)));
typedef _Float16 f16x4 __attribute__((ext_vector_type(4)));
typedef _Float16 f16x2 __attribute__((ext_vector_type(2)));
typedef float f32x4 __attribute__((ext_vector_type(4)));

// ---------------- x fp32 [b][384][NPIX] -> XT f16 [b][NPIX][384]
__global__ void convert_xt_kernel(const float* __restrict__ In, _Float16* __restrict__ Out) {
    const int b = blockIdx.z;
    In  += (size_t)b * DIM * NPIX;
    Out += (size_t)b * NPIX * DIM;
    __shared__ _Float16 t[128][66];
    const int tid = threadIdx.x;
    const int n0 = blockIdx.x * 64, c0 = blockIdx.y * 128;
    const int col = tid & 63, rb = tid >> 6;
#pragma unroll
    for (int i = 0; i < 32; ++i) {
        const int r = i * 4 + rb;   // c-local
        t[r][col] = (_Float16)In[(size_t)(c0 + r) * NPIX + n0 + col];
    }
    __syncthreads();
#pragma unroll
    for (int i = 0; i < 16; ++i) {
        const int n = i * 4 + rb;   // n-local
        f16x2 v;
        v[0] = t[col * 2][n];
        v[1] = t[col * 2 + 1][n];
        *(f16x2*)&Out[(size_t)(n0 + n) * DIM + c0 + col * 2] = v;
    }
}

// ---------------- W fp32 -> f16
__global__ void convert_w_kernel(const float* __restrict__ W, _Float16* __restrict__ O, int n4) {
    const int i = blockIdx.x * 256 + threadIdx.x;
    if (i >= n4) return;
    const float4 v = reinterpret_cast<const float4*>(W)[i];
    _Float16* o = O + (size_t)i * 4;
    o[0] = (_Float16)v.x; o[1] = (_Float16)v.y; o[2] = (_Float16)v.z; o[3] = (_Float16)v.w;
}

// ---------------- MFMA GEMM (R17 frozen): 128x128, BK=64, dbuf LDS, XOR swizzle,
// XCD-aware bijective block swizzle, LDS-staged vectorized epilogue.
template<typename OutT>
__global__ void gemm16_kernel(const _Float16* __restrict__ A, const _Float16* __restrict__ BT,
                              OutT* __restrict__ Y, size_t astride, size_t bstride, size_t ystride) {
    __shared__ __attribute__((aligned(16))) char smem[65536];  // A:2x16KB | B:2x16KB, reused for C
    const int tid = threadIdx.x;
    const int lane = tid & 63, wid = tid >> 6;
    const int gx = gridDim.x, gy = gridDim.y;
    const int Dl = blockIdx.x + gx * (blockIdx.y + gy * blockIdx.z);
    const int T  = gx * gy * (int)gridDim.z;
    const int S  = (Dl & 7) * (T >> 3) + (Dl >> 3);
    const int m0 = (S % gy) * 128;
    const int rest = S / gy;
    const int n0 = (rest % gx) * 128;
    const int zi = rest / gx;
    A  += (size_t)zi * astride;
    BT += (size_t)zi * bstride;
    Y  += (size_t)zi * ystride;
    const int wrow = (wid >> 1) * 64, wcol = (wid & 1) * 64;

    auto stage = [&](int buf, int t) {
        const int k0 = t * 64;
#pragma unroll
        for (int issue = 0; issue < 4; ++issue) {
            const int p = issue * 4096 + wid * 1024 + lane * 16;   // linear LDS byte pos
            const int row = p >> 7;
            const int cb  = (p & 127) ^ ((row & 7) << 4);          // swizzled source col-bytes
            const int kp  = cb >> 1;
            __builtin_amdgcn_global_load_lds(
                (const __attribute__((address_space(1))) void*)&A[(size_t)(m0 + row) * 384 + k0 + kp],
                (__attribute__((address_space(3))) void*)(smem + buf * 16384 + p), 16, 0, 0);
            __builtin_amdgcn_global_load_lds(
                (const __attribute__((address_space(1))) void*)&BT[(size_t)(n0 + row) * 384 + k0 + kp],
                (__attribute__((address_space(3))) void*)(smem + 32768 + buf * 16384 + p), 16, 0, 0);
        }
    };

    f32x4 acc[4][4] = {};
    stage(0, 0);
    __syncthreads();
    int cur = 0;
    for (int t = 0; t < 6; ++t) {
        if (t + 1 < 6) stage(cur ^ 1, t + 1);   // prefetch overlaps compute below
        const char* Ab = smem + cur * 16384;
        const char* Bb = smem + 32768 + cur * 16384;
#pragma unroll
        for (int ksub = 0; ksub < 2; ++ksub) {
            const int cb = ksub * 64 + (lane >> 4) * 16;   // byte col within row
            f16x8 af[4], bf[4];
#pragma unroll
            for (int mi = 0; mi < 4; ++mi) {
                const int r = wrow + mi * 16 + (lane & 15);
                af[mi] = *(const f16x8*)(Ab + r * 128 + (cb ^ ((r & 7) << 4)));
            }
#pragma unroll
            for (int ni = 0; ni < 4; ++ni) {
                const int r = wcol + ni * 16 + (lane & 15);
                bf[ni] = *(const f16x8*)(Bb + r * 128 + (cb ^ ((r & 7) << 4)));
            }
#pragma unroll
            for (int mi = 0; mi < 4; ++mi)
#pragma unroll
                for (int ni = 0; ni < 4; ++ni)
                    acc[mi][ni] = __builtin_amdgcn_mfma_f32_16x16x32_f16(af[mi], bf[ni], acc[mi][ni], 0, 0, 0);
        }
        __syncthreads();
        cur ^= 1;
    }
    // --- epilogue: C tile -> swizzled LDS -> coalesced 16B stores
    constexpr int EB = (int)sizeof(OutT);         // 2 or 4
    constexpr int ROWB = 128 * EB;                // LDS bytes per C row
#pragma unroll
    for (int mi = 0; mi < 4; ++mi)
#pragma unroll
        for (int ni = 0; ni < 4; ++ni) {
            const int col = wcol + ni * 16 + (lane & 15);
#pragma unroll
            for (int r = 0; r < 4; ++r) {
                const int row = wrow + mi * 16 + (lane >> 4) * 4 + r;
                *(OutT*)(smem + row * ROWB + ((col * EB) ^ ((row & 7) << 4))) = (OutT)acc[mi][ni][r];
            }
        }
    __syncthreads();
    constexpr int CPR = ROWB / 16;                // 16B chunks per row (16 or 32)
    constexpr int ITER = 128 * CPR / 256;         // 8 or 16
#pragma unroll
    for (int i = 0; i < ITER; ++i) {
        const int idx = i * 256 + tid;
        const int row = idx / CPR, ch = idx % CPR;
        *(uint4*)&Y[(size_t)(m0 + row) * NPIX + n0 + ch * (16 / EB)] =
            *(const uint4*)(smem + row * ROWB + ((ch * 16) ^ ((row & 7) << 4)));
    }
}

// ---------------- depthwise 3x3 pad=1 for q,k channels; out [b][768][NPIX]
// 2-output-row strips, 16 px/thread-row: 4 input rows serve 32 outputs.
// 48 strips x 6 x-positions per channel-image; strip x-edges == image x-edges.
__global__ void dwconv_qk_kernel(const _Float16* __restrict__ In, const float* __restrict__ Wd,
                                 _Float16* __restrict__ Out) {
    const int idx = blockIdx.x * 256 + threadIdx.x;   // over NB*768*288
    const int lane = threadIdx.x & 63;
    const int ci = idx / 288;                          // [0, NB*768)
    const int rem = idx - ci * 288;
    const int strip = rem / 6, xpos = rem - strip * 6;
    const int b = ci / 768, c = ci % 768;
    const _Float16* ip = In + ((size_t)b * OC3 + c) * NPIX;
    const float* w = &Wd[c * 9];
    const int y = strip * 2, x0 = xpos * 16;
    float o0[16] = {}, o1[16] = {};
#pragma unroll
    for (int r = 0; r < 4; ++r) {
        const int yy = y - 1 + r;
        if (yy < 0 || yy >= HH) continue;
        const _Float16* row = ip + yy * WW;
        const f16x8 m0 = *(const f16x8*)&row[x0];
        const f16x8 m1 = *(const f16x8*)&row[x0 + 8];
        float v[18];
#pragma unroll
        for (int j = 0; j < 8; ++j) { v[j + 1] = (float)m0[j]; v[j + 9] = (float)m1[j]; }
        float left  = __shfl_up(v[16], 1);    // lane-1 = xpos-1 of same strip (when xpos>0)
        float right = __shfl_down(v[1], 1);   // lane+1 = xpos+1 of same strip (when xpos<5)
        if (lane == 0  && xpos > 0) left  = (float)row[x0 - 1];
        if (lane == 63 && xpos < 5) right = (float)row[x0 + 16];
        v[0]  = (xpos > 0) ? left  : 0.f;
        v[17] = (xpos < 5) ? right : 0.f;
        if (r < 3) {   // contributes to output row y with weight row r
            const float w0 = w[r * 3], w1 = w[r * 3 + 1], w2 = w[r * 3 + 2];
#pragma unroll
            for (int j = 0; j < 16; ++j) o0[j] += w0 * v[j] + w1 * v[j + 1] + w2 * v[j + 2];
        }
        if (r > 0) {   // contributes to output row y+1 with weight row r-1
            const float w0 = w[(r - 1) * 3], w1 = w[(r - 1) * 3 + 1], w2 = w[(r - 1) * 3 + 2];
#pragma unroll
            for (int j = 0; j < 16; ++j) o1[j] += w0 * v[j] + w1 * v[j + 1] + w2 * v[j + 2];
        }
    }
    f16x8 r0, r1, r2, r3;
#pragma unroll
    for (int j = 0; j < 8; ++j) {
        r0[j] = (_Float16)o0[j]; r1[j] = (_Float16)o0[j + 8];
        r2[j] = (_Float16)o1[j]; r3[j] = (_Float16)o1[j + 8];
    }
    _Float16* op = Out + (size_t)ci * NPIX + y * WW + x0;
    *(f16x8*)&op[0]      = r0;
    *(f16x8*)&op[8]      = r1;
    *(f16x8*)&op[WW]     = r2;
    *(f16x8*)&op[WW + 8] = r3;
}

// ---------------- depthwise 3x3 for v channels + transposed write vT[b][n][384]
// 256-px tiles, 16 px/thread: grid (NPIX/256, HEADS, NB), block 256.
__global__ void dwconv_vt_kernel(const _Float16* __restrict__ In, const float* __restrict__ Wd,
                                 unsigned* __restrict__ OutT) {
    const int pt = blockIdx.x, h = blockIdx.y, b = blockIdx.z;
    const int n0 = pt * 256;
    const int tid = threadIdx.x, lane = tid & 63;
    __shared__ _Float16 tt[48][264];   // [c][px 256], padded
    const int px0 = (tid & 15) * 16;
    const int cg = tid >> 4;            // 16 groups x 3 channels
    const int p0 = n0 + px0;
    const int y = p0 / WW, x0 = p0 % WW;   // 96%16==0 -> 16px stay in one image row
#pragma unroll
    for (int i = 0; i < 3; ++i) {
        const int c = cg * 3 + i;
        const _Float16* ip = In + ((size_t)b * OC3 + 2 * DIM + h * HD + c) * NPIX;
        const float* w = &Wd[(2 * DIM + h * HD + c) * 9];
        float o[16] = {};
#pragma unroll
        for (int dy = -1; dy <= 1; ++dy) {
            const int yy = y + dy;
            if (yy < 0 || yy >= HH) continue;
            const _Float16* row = ip + yy * WW;
            const f16x8 m0 = *(const f16x8*)&row[x0];
            const f16x8 m1 = *(const f16x8*)&row[x0 + 8];
            float v[18];
#pragma unroll
            for (int j = 0; j < 8; ++j) { v[j + 1] = (float)m0[j]; v[j + 9] = (float)m1[j]; }
            float left  = __shfl_up(v[16], 1);
            float right = __shfl_down(v[1], 1);
            if ((lane & 15) == 0  && x0 > 0)        left  = (float)row[x0 - 1];
            if ((lane & 15) == 15 && x0 + 16 < WW)  right = (float)row[x0 + 16];
            v[0]  = (x0 > 0)       ? left  : 0.f;
            v[17] = (x0 + 16 < WW) ? right : 0.f;
            const float w0 = w[(dy + 1) * 3], w1 = w[(dy + 1) * 3 + 1], w2 = w[(dy + 1) * 3 + 2];
#pragma unroll
            for (int j = 0; j < 16; ++j) o[j] += w0 * v[j] + w1 * v[j + 1] + w2 * v[j + 2];
        }
        f16x8 r0, r1;
#pragma unroll
        for (int j = 0; j < 8; ++j) { r0[j] = (_Float16)o[j]; r1[j] = (_Float16)o[j + 8]; }
        *(f16x8*)&tt[c][px0] = r0;
        *(f16x8*)&tt[c][px0 + 8] = r1;
    }
    __syncthreads();
    // write vT rows: 256 px x 24 u32 (48 halves)
#pragma unroll
    for (int it = 0; it < 24; ++it) {
        const int i = it * 256 + tid;          // < 6144
        const int r = i / 24, c2 = i % 24;
        union { _Float16 hh[2]; unsigned u; } pk;
        pk.hh[0] = tt[2 * c2][r];
        pk.hh[1] = tt[2 * c2 + 1][r];
        OutT[((size_t)b * NPIX + n0 + r) * 192 + h * 24 + c2] = pk.u;
    }
}

// ---------------- MFMA gram; sumsq ALSO via MFMA (diag of q.q^T / k.k^T)
__global__ void gram16_kernel(const _Float16* __restrict__ QK, float* __restrict__ P,
                              float* __restrict__ SS) {
    const int h = blockIdx.y, s = blockIdx.x, b = blockIdx.z;
    QK += (size_t)b * 768 * NPIX;
    const int tid = threadIdx.x;
    const int lane = tid & 63, wave = tid >> 6;
    const _Float16* q = QK + (size_t)(h * HD) * NPIX;
    const _Float16* k = QK + (size_t)(DIM + h * HD) * NPIX;
    const int rowa = lane & 15, koff = (lane >> 4) * 8;
    f32x4 acc[3][3] = {};
    f32x4 aqq[3] = {}, akk[3] = {};
#pragma unroll
    for (int kk = 0; kk < 4; ++kk) {
        const int nk = s * 256 + wave * 128 + kk * 32 + koff;
        f16x8 aq[3], bk[3];
#pragma unroll
        for (int i = 0; i < 3; ++i)
            aq[i] = *(const f16x8*)&q[(size_t)(i * 16 + rowa) * NPIX + nk];
#pragma unroll
        for (int j = 0; j < 3; ++j)
            bk[j] = *(const f16x8*)&k[(size_t)(j * 16 + rowa) * NPIX + nk];
#pragma unroll
        for (int i = 0; i < 3; ++i) {
            aqq[i] = __builtin_amdgcn_mfma_f32_16x16x32_f16(aq[i], aq[i], aqq[i], 0, 0, 0);
            akk[i] = __builtin_amdgcn_mfma_f32_16x16x32_f16(bk[i], bk[i], akk[i], 0, 0, 0);
        }
#pragma unroll
        for (int i = 0; i < 3; ++i)
#pragma unroll
            for (int j = 0; j < 3; ++j)
                acc[i][j] = __builtin_amdgcn_mfma_f32_16x16x32_f16(aq[i], bk[j], acc[i][j], 0, 0, 0);
    }
    // diag of q.q^T: row==col=c lives at lane = c + 16*(c>>2), reg r = c&3
    const int cd = lane & 15;
    if ((lane >> 4) == (cd >> 2)) {
        float* ssb = SS + (((size_t)(b * HEADS + h) * NCH + s) * 2 + wave) * 96;
#pragma unroll
        for (int i = 0; i < 3; ++i) {
            ssb[i * 16 + cd]      = aqq[i][cd & 3];
            ssb[48 + i * 16 + cd] = akk[i][cd & 3];
        }
    }
    __shared__ float red[2][HD][HD];
#pragma unroll
    for (int i = 0; i < 3; ++i)
#pragma unroll
        for (int j = 0; j < 3; ++j)
#pragma unroll
            for (int r = 0; r < 4; ++r)
                red[wave][i * 16 + (lane >> 4) * 4 + r][j * 16 + (lane & 15)] = acc[i][j][r];
    __syncthreads();
    float* pp = P + ((size_t)(b * HEADS + h) * NCH + s) * HD * HD;
    for (int idx = tid; idx < HD * HD; idx += 128)
        pp[idx] = (&red[0][0][0])[idx] + (&red[1][0][0])[idx];
}

// ---------------- reduce sumsq partials -> 1/max(||row||,eps)
__global__ void normreduce_kernel(const float* __restrict__ SS, float* __restrict__ Fn) {
    const int idx = blockIdx.x * 256 + threadIdx.x;
    if (idx >= NB * 768) return;
    const int b = idx / 768, r = idx % 768;
    const int qk = r >= 384;
    const int h = (r - qk * 384) / HD, c = r % HD;
    const float* base = SS + ((size_t)(b * HEADS + h) * NCH) * 2 * 96 + qk * 48 + c;
    float s = 0.f;
    for (int u = 0; u < NCH * 2; ++u) s += base[u * 96];
    Fn[b * 768 + r] = 1.f / fmaxf(sqrtf(s), 1e-12f);
}

// ---------------- reduce gram partials, scale by norms+temp, softmax over d
__global__ void softmax_kernel(const float* __restrict__ P, const float* __restrict__ Fn,
                               const float* __restrict__ temp, float* __restrict__ A) {
    const int b = blockIdx.y;
    const int h = blockIdx.x / HD, c = blockIdx.x % HD;
    const float* F = Fn + b * 768;
    const float* Pb = P + (size_t)b * HEADS * NCH * HD * HD;
    const int d = threadIdx.x;
    float val = 0.f, v = -INFINITY;
    if (d < HD) {
        float sum = 0.f;
        for (int s = 0; s < NCH; ++s) sum += Pb[((size_t)(h * NCH + s) * HD + c) * HD + d];
        val = sum * F[h * HD + c] * F[DIM + h * HD + d] * temp[h];
        v = val;
    }
    float m = v;
    for (int off = 32; off; off >>= 1) m = fmaxf(m, __shfl_xor(m, off));
    const float e = (d < HD) ? expf(val - m) : 0.f;
    float se = e;
    for (int off = 32; off; off >>= 1) se += __shfl_xor(se, off);
    if (d < HD) A[((size_t)b * HEADS + h) * HD * HD + (size_t)c * HD + d] = e / se;
}

// ---------------- WP_eff[b][o][h*48+d] = sum_c wp[o][h*48+c]*attn[b][h][c][d]
__global__ void wpeff_kernel(const float* __restrict__ Wp, const float* __restrict__ At,
                             _Float16* __restrict__ WPe) {
    const int og = blockIdx.x, h = blockIdx.y, b = blockIdx.z;
    const int o0 = og * 48;
    const int tid = threadIdx.x;
    __shared__ float as2[HD][HD];   // attn[c][d]
    __shared__ float wpb[HD][HD];   // wp[o0+r][h*48+c]
    const float* ab = At + ((size_t)(b * HEADS + h)) * HD * HD;
    for (int wi = tid; wi < HD * HD; wi += 256) {
        (&as2[0][0])[wi] = ab[wi];
        wpb[wi / HD][wi % HD] = Wp[(size_t)(o0 + wi / HD) * DIM + h * HD + wi % HD];
    }
    __syncthreads();
#pragma unroll
    for (int it = 0; it < 3; ++it) {
        const int wi = it * 256 + tid;       // 48o * 12 d-quads = 576
        if (wi >= 576) break;
        const int ol = wi / 12, d0 = (wi % 12) * 4;
        f32x4 acc = {};
#pragma unroll
        for (int c = 0; c < HD; ++c) {
            const float wv = wpb[ol][c];
            const f32x4 a4 = *(const f32x4*)&as2[c][d0];
            acc.x += wv * a4.x; acc.y += wv * a4.y; acc.z += wv * a4.z; acc.w += wv * a4.w;
        }
        f16x4 r;
        r[0] = (_Float16)acc.x; r[1] = (_Float16)acc.y;
        r[2] = (_Float16)acc.z; r[3] = (_Float16)acc.w;
        *(f16x4*)&WPe[((size_t)b * DIM + o0 + ol) * DIM + h * HD + d0] = r;
    }
}

extern "C" void kernel_launch(void* const* d_in, const int* in_sizes, int n_in,
                              void* d_out, int out_size, void* d_ws, size_t ws_size,
                              hipStream_t stream) {
    const float* x      = (const float*)d_in[0];
    const float* w_qkv  = (const float*)d_in[1];
    const float* w_dw   = (const float*)d_in[2];
    const float* w_proj = (const float*)d_in[3];
    const float* temp   = (const float*)d_in[4];
    float* out = (float*)d_out;

    char* ws = (char*)d_ws;
    const size_t SZ_XT  = (size_t)NB * NPIX * DIM * 2;   // 28.3 MB
    const size_t SZ_QKV = (size_t)NB * OC3 * NPIX * 2;   // 84.9 MB
    const size_t SZ_QK  = (size_t)NB * 768 * NPIX * 2;   // 56.6 MB
    const size_t SZ_VT  = SZ_XT;                          // 28.3 MB
    _Float16* XT      = (_Float16*)(ws);
    _Float16* qkv16   = (_Float16*)(ws + SZ_XT);
    _Float16* qkdw16  = (_Float16*)(ws + SZ_XT + SZ_QKV);
    _Float16* vT16    = (_Float16*)(ws + SZ_XT + SZ_QKV + SZ_QK);
    char* tail = ws + SZ_XT + SZ_QKV + SZ_QK + SZ_VT;
    _Float16* W16q = (_Float16*)(tail);                              // 884736 B
    float*    Fn   = (float*)(tail + 1024 * 1024);                   // 12KB
    float*    Pp   = (float*)(tail + 1024 * 1024 + 65536);           // 10.6 MB
    float*    At   = (float*)(tail + 12 * 1024 * 1024);              // 294912 B
    float*    SS   = (float*)(tail + 13 * 1024 * 1024);              // 884736 B
    _Float16* WPe  = (_Float16*)(tail + 14 * 1024 * 1024);           // 1.18 MB

    convert_w_kernel<<<(OC3 * DIM / 4 + 255) / 256, 256, 0, stream>>>(w_qkv, W16q, OC3 * DIM / 4);

    convert_xt_kernel<<<dim3(NPIX / 64, DIM / 128, NB), 256, 0, stream>>>(x, XT);
    gemm16_kernel<_Float16><<<dim3(NPIX / 128, OC3 / 128, NB), 256, 0, stream>>>(
        W16q, XT, qkv16, 0, (size_t)NPIX * DIM, (size_t)OC3 * NPIX);
    dwconv_qk_kernel<<<(NB * 768 * 288) / 256, 256, 0, stream>>>(qkv16, w_dw, qkdw16);
    dwconv_vt_kernel<<<dim3(NPIX / 256, HEADS, NB), 256, 0, stream>>>(
        qkv16, w_dw, (unsigned*)vT16);
    gram16_kernel<<<dim3(NCH, HEADS, NB), 128, 0, stream>>>(qkdw16, Pp, SS);
    normreduce_kernel<<<(NB * 768 + 255) / 256, 256, 0, stream>>>(SS, Fn);
    softmax_kernel<<<dim3(HEADS * HD, NB), 64, 0, stream>>>(Pp, Fn, temp, At);
    wpeff_kernel<<<dim3(8, HEADS, NB), 256, 0, stream>>>(w_proj, At, WPe);
    gemm16_kernel<float><<<dim3(NPIX / 128, DIM / 128, NB), 256, 0, stream>>>(
        WPe, vT16, out, (size_t)DIM * DIM, (size_t)NPIX * DIM, (size_t)DIM * NPIX);
}

// Round 19
// 166.373 us; speedup vs baseline: 1.0189x; 1.0189x over previous
//
#include <hip/hip_runtime.h>
#include <hip/hip_bf16.h>
#include <math.h>

#define DIM   384
#define HEADS 8
#define HD    48
#define HH    96
#define WW    96
#define NPIX  9216
#define OC3   1152
#define NCH   36      // gram n-chunks (36*256 = 9216)
#define NB    4

typedef _Float16 f16x8 __attribute__((ext_vector_type(8)));
typedef _Float16 f16x4 __attribute__((ext_vector_type(4)));
typedef _Float16 f16x2 __attribute__((ext_vector_type(2)));
typedef float f32x4 __attribute__((ext_vector_type(4)));

// ---------------- x fp32 [b][384][NPIX] -> XT f16 [b][NPIX][384]
__global__ void convert_xt_kernel(const float* __restrict__ In, _Float16* __restrict__ Out) {
    const int b = blockIdx.z;
    In  += (size_t)b * DIM * NPIX;
    Out += (size_t)b * NPIX * DIM;
    __shared__ _Float16 t[128][66];
    const int tid = threadIdx.x;
    const int n0 = blockIdx.x * 64, c0 = blockIdx.y * 128;
    const int col = tid & 63, rb = tid >> 6;
#pragma unroll
    for (int i = 0; i < 32; ++i) {
        const int r = i * 4 + rb;   // c-local
        t[r][col] = (_Float16)In[(size_t)(c0 + r) * NPIX + n0 + col];
    }
    __syncthreads();
#pragma unroll
    for (int i = 0; i < 16; ++i) {
        const int n = i * 4 + rb;   // n-local
        f16x2 v;
        v[0] = t[col * 2][n];
        v[1] = t[col * 2 + 1][n];
        *(f16x2*)&Out[(size_t)(n0 + n) * DIM + c0 + col * 2] = v;
    }
}

// ---------------- W fp32 -> f16
__global__ void convert_w_kernel(const float* __restrict__ W, _Float16* __restrict__ O, int n4) {
    const int i = blockIdx.x * 256 + threadIdx.x;
    if (i >= n4) return;
    const float4 v = reinterpret_cast<const float4*>(W)[i];
    _Float16* o = O + (size_t)i * 4;
    o[0] = (_Float16)v.x; o[1] = (_Float16)v.y; o[2] = (_Float16)v.z; o[3] = (_Float16)v.w;
}

// ---------------- MFMA GEMM (R17 frozen): 128x128, BK=64, dbuf LDS, XOR swizzle,
// XCD-aware bijective block swizzle, LDS-staged vectorized epilogue.
template<typename OutT>
__global__ void gemm16_kernel(const _Float16* __restrict__ A, const _Float16* __restrict__ BT,
                              OutT* __restrict__ Y, size_t astride, size_t bstride, size_t ystride) {
    __shared__ __attribute__((aligned(16))) char smem[65536];  // A:2x16KB | B:2x16KB, reused for C
    const int tid = threadIdx.x;
    const int lane = tid & 63, wid = tid >> 6;
    const int gx = gridDim.x, gy = gridDim.y;
    const int Dl = blockIdx.x + gx * (blockIdx.y + gy * blockIdx.z);
    const int T  = gx * gy * (int)gridDim.z;
    const int S  = (Dl & 7) * (T >> 3) + (Dl >> 3);
    const int m0 = (S % gy) * 128;
    const int rest = S / gy;
    const int n0 = (rest % gx) * 128;
    const int zi = rest / gx;
    A  += (size_t)zi * astride;
    BT += (size_t)zi * bstride;
    Y  += (size_t)zi * ystride;
    const int wrow = (wid >> 1) * 64, wcol = (wid & 1) * 64;

    auto stage = [&](int buf, int t) {
        const int k0 = t * 64;
#pragma unroll
        for (int issue = 0; issue < 4; ++issue) {
            const int p = issue * 4096 + wid * 1024 + lane * 16;   // linear LDS byte pos
            const int row = p >> 7;
            const int cb  = (p & 127) ^ ((row & 7) << 4);          // swizzled source col-bytes
            const int kp  = cb >> 1;
            __builtin_amdgcn_global_load_lds(
                (const __attribute__((address_space(1))) void*)&A[(size_t)(m0 + row) * 384 + k0 + kp],
                (__attribute__((address_space(3))) void*)(smem + buf * 16384 + p), 16, 0, 0);
            __builtin_amdgcn_global_load_lds(
                (const __attribute__((address_space(1))) void*)&BT[(size_t)(n0 + row) * 384 + k0 + kp],
                (__attribute__((address_space(3))) void*)(smem + 32768 + buf * 16384 + p), 16, 0, 0);
        }
    };

    f32x4 acc[4][4] = {};
    stage(0, 0);
    __syncthreads();
    int cur = 0;
    for (int t = 0; t < 6; ++t) {
        if (t + 1 < 6) stage(cur ^ 1, t + 1);   // prefetch overlaps compute below
        const char* Ab = smem + cur * 16384;
        const char* Bb = smem + 32768 + cur * 16384;
#pragma unroll
        for (int ksub = 0; ksub < 2; ++ksub) {
            const int cb = ksub * 64 + (lane >> 4) * 16;   // byte col within row
            f16x8 af[4], bf[4];
#pragma unroll
            for (int mi = 0; mi < 4; ++mi) {
                const int r = wrow + mi * 16 + (lane & 15);
                af[mi] = *(const f16x8*)(Ab + r * 128 + (cb ^ ((r & 7) << 4)));
            }
#pragma unroll
            for (int ni = 0; ni < 4; ++ni) {
                const int r = wcol + ni * 16 + (lane & 15);
                bf[ni] = *(const f16x8*)(Bb + r * 128 + (cb ^ ((r & 7) << 4)));
            }
#pragma unroll
            for (int mi = 0; mi < 4; ++mi)
#pragma unroll
                for (int ni = 0; ni < 4; ++ni)
                    acc[mi][ni] = __builtin_amdgcn_mfma_f32_16x16x32_f16(af[mi], bf[ni], acc[mi][ni], 0, 0, 0);
        }
        __syncthreads();
        cur ^= 1;
    }
    // --- epilogue: C tile -> swizzled LDS -> coalesced 16B stores
    constexpr int EB = (int)sizeof(OutT);         // 2 or 4
    constexpr int ROWB = 128 * EB;                // LDS bytes per C row
#pragma unroll
    for (int mi = 0; mi < 4; ++mi)
#pragma unroll
        for (int ni = 0; ni < 4; ++ni) {
            const int col = wcol + ni * 16 + (lane & 15);
#pragma unroll
            for (int r = 0; r < 4; ++r) {
                const int row = wrow + mi * 16 + (lane >> 4) * 4 + r;
                *(OutT*)(smem + row * ROWB + ((col * EB) ^ ((row & 7) << 4))) = (OutT)acc[mi][ni][r];
            }
        }
    __syncthreads();
    constexpr int CPR = ROWB / 16;                // 16B chunks per row (16 or 32)
    constexpr int ITER = 128 * CPR / 256;         // 8 or 16
#pragma unroll
    for (int i = 0; i < ITER; ++i) {
        const int idx = i * 256 + tid;
        const int row = idx / CPR, ch = idx % CPR;
        *(uint4*)&Y[(size_t)(m0 + row) * NPIX + n0 + ch * (16 / EB)] =
            *(const uint4*)(smem + row * ROWB + ((ch * 16) ^ ((row & 7) << 4)));
    }
}

// ---------------- depthwise 3x3 pad=1 for q,k channels; out [b][768][NPIX]
// R17-proven: 16 px/thread, 1 output row, halos via shuffle.
__global__ void dwconv_qk_kernel(const _Float16* __restrict__ In, const float* __restrict__ Wd,
                                 _Float16* __restrict__ Out) {
    const int idx = blockIdx.x * 256 + threadIdx.x;   // over NB*768*576
    const int lane = threadIdx.x & 63;
    const int ci = idx / 576;                          // [0, NB*768)
    const int p0 = (idx - ci * 576) * 16;              // 96%16==0 -> same image row
    const int b = ci / 768, c = ci % 768;
    const _Float16* ip = In + ((size_t)b * OC3 + c) * NPIX;
    const float* w = &Wd[c * 9];
    const int y = p0 / WW, x0 = p0 % WW;
    float o[16] = {};
#pragma unroll
    for (int dy = -1; dy <= 1; ++dy) {
        const int yy = y + dy;
        if (yy < 0 || yy >= HH) continue;
        const _Float16* row = ip + yy * WW;
        const f16x8 m0 = *(const f16x8*)&row[x0];
        const f16x8 m1 = *(const f16x8*)&row[x0 + 8];
        float v[18];
#pragma unroll
        for (int j = 0; j < 8; ++j) { v[j + 1] = (float)m0[j]; v[j + 9] = (float)m1[j]; }
        float left  = __shfl_up(v[16], 1);    // lane-1's last px == p0-1
        float right = __shfl_down(v[1], 1);   // lane+1's first px == p0+16
        if (lane == 0  && x0 > 0)        left  = (float)row[x0 - 1];
        if (lane == 63 && x0 + 16 < WW)  right = (float)row[x0 + 16];
        v[0]  = (x0 > 0)       ? left  : 0.f;
        v[17] = (x0 + 16 < WW) ? right : 0.f;
        const float w0 = w[(dy + 1) * 3], w1 = w[(dy + 1) * 3 + 1], w2 = w[(dy + 1) * 3 + 2];
#pragma unroll
        for (int j = 0; j < 16; ++j) o[j] += w0 * v[j] + w1 * v[j + 1] + w2 * v[j + 2];
    }
    f16x8 r0, r1;
#pragma unroll
    for (int j = 0; j < 8; ++j) { r0[j] = (_Float16)o[j]; r1[j] = (_Float16)o[j + 8]; }
    *(f16x8*)&Out[(size_t)ci * NPIX + p0] = r0;
    *(f16x8*)&Out[(size_t)ci * NPIX + p0 + 8] = r1;
}

// ---------------- depthwise 3x3 for v channels + transposed write vT[b][n][384]
// 256-px tiles, 16 px/thread: grid (NPIX/256, HEADS, NB), block 256.
__global__ void dwconv_vt_kernel(const _Float16* __restrict__ In, const float* __restrict__ Wd,
                                 unsigned* __restrict__ OutT) {
    const int pt = blockIdx.x, h = blockIdx.y, b = blockIdx.z;
    const int n0 = pt * 256;
    const int tid = threadIdx.x, lane = tid & 63;
    __shared__ _Float16 tt[48][264];   // [c][px 256], padded
    const int px0 = (tid & 15) * 16;
    const int cg = tid >> 4;            // 16 groups x 3 channels
    const int p0 = n0 + px0;
    const int y = p0 / WW, x0 = p0 % WW;   // 96%16==0 -> 16px stay in one image row
#pragma unroll
    for (int i = 0; i < 3; ++i) {
        const int c = cg * 3 + i;
        const _Float16* ip = In + ((size_t)b * OC3 + 2 * DIM + h * HD + c) * NPIX;
        const float* w = &Wd[(2 * DIM + h * HD + c) * 9];
        float o[16] = {};
#pragma unroll
        for (int dy = -1; dy <= 1; ++dy) {
            const int yy = y + dy;
            if (yy < 0 || yy >= HH) continue;
            const _Float16* row = ip + yy * WW;
            const f16x8 m0 = *(const f16x8*)&row[x0];
            const f16x8 m1 = *(const f16x8*)&row[x0 + 8];
            float v[18];
#pragma unroll
            for (int j = 0; j < 8; ++j) { v[j + 1] = (float)m0[j]; v[j + 9] = (float)m1[j]; }
            float left  = __shfl_up(v[16], 1);
            float right = __shfl_down(v[1], 1);
            if ((lane & 15) == 0  && x0 > 0)        left  = (float)row[x0 - 1];
            if ((lane & 15) == 15 && x0 + 16 < WW)  right = (float)row[x0 + 16];
            v[0]  = (x0 > 0)       ? left  : 0.f;
            v[17] = (x0 + 16 < WW) ? right : 0.f;
            const float w0 = w[(dy + 1) * 3], w1 = w[(dy + 1) * 3 + 1], w2 = w[(dy + 1) * 3 + 2];
#pragma unroll
            for (int j = 0; j < 16; ++j) o[j] += w0 * v[j] + w1 * v[j + 1] + w2 * v[j + 2];
        }
        f16x8 r0, r1;
#pragma unroll
        for (int j = 0; j < 8; ++j) { r0[j] = (_Float16)o[j]; r1[j] = (_Float16)o[j + 8]; }
        *(f16x8*)&tt[c][px0] = r0;
        *(f16x8*)&tt[c][px0 + 8] = r1;
    }
    __syncthreads();
    // write vT rows: 256 px x 24 u32 (48 halves)
#pragma unroll
    for (int it = 0; it < 24; ++it) {
        const int i = it * 256 + tid;          // < 6144
        const int r = i / 24, c2 = i % 24;
        union { _Float16 hh[2]; unsigned u; } pk;
        pk.hh[0] = tt[2 * c2][r];
        pk.hh[1] = tt[2 * c2 + 1][r];
        OutT[((size_t)b * NPIX + n0 + r) * 192 + h * 24 + c2] = pk.u;
    }
}

// ---------------- MFMA gram; sumsq ALSO via MFMA (diag of q.q^T / k.k^T)
__global__ void gram16_kernel(const _Float16* __restrict__ QK, float* __restrict__ P,
                              float* __restrict__ SS) {
    const int h = blockIdx.y, s = blockIdx.x, b = blockIdx.z;
    QK += (size_t)b * 768 * NPIX;
    const int tid = threadIdx.x;
    const int lane = tid & 63, wave = tid >> 6;
    const _Float16* q = QK + (size_t)(h * HD) * NPIX;
    const _Float16* k = QK + (size_t)(DIM + h * HD) * NPIX;
    const int rowa = lane & 15, koff = (lane >> 4) * 8;
    f32x4 acc[3][3] = {};
    f32x4 aqq[3] = {}, akk[3] = {};
#pragma unroll
    for (int kk = 0; kk < 4; ++kk) {
        const int nk = s * 256 + wave * 128 + kk * 32 + koff;
        f16x8 aq[3], bk[3];
#pragma unroll
        for (int i = 0; i < 3; ++i)
            aq[i] = *(const f16x8*)&q[(size_t)(i * 16 + rowa) * NPIX + nk];
#pragma unroll
        for (int j = 0; j < 3; ++j)
            bk[j] = *(const f16x8*)&k[(size_t)(j * 16 + rowa) * NPIX + nk];
#pragma unroll
        for (int i = 0; i < 3; ++i) {
            aqq[i] = __builtin_amdgcn_mfma_f32_16x16x32_f16(aq[i], aq[i], aqq[i], 0, 0, 0);
            akk[i] = __builtin_amdgcn_mfma_f32_16x16x32_f16(bk[i], bk[i], akk[i], 0, 0, 0);
        }
#pragma unroll
        for (int i = 0; i < 3; ++i)
#pragma unroll
            for (int j = 0; j < 3; ++j)
                acc[i][j] = __builtin_amdgcn_mfma_f32_16x16x32_f16(aq[i], bk[j], acc[i][j], 0, 0, 0);
    }
    // diag of q.q^T: row==col=c lives at lane = c + 16*(c>>2), reg r = c&3
    const int cd = lane & 15;
    if ((lane >> 4) == (cd >> 2)) {
        float* ssb = SS + (((size_t)(b * HEADS + h) * NCH + s) * 2 + wave) * 96;
#pragma unroll
        for (int i = 0; i < 3; ++i) {
            ssb[i * 16 + cd]      = aqq[i][cd & 3];
            ssb[48 + i * 16 + cd] = akk[i][cd & 3];
        }
    }
    __shared__ float red[2][HD][HD];
#pragma unroll
    for (int i = 0; i < 3; ++i)
#pragma unroll
        for (int j = 0; j < 3; ++j)
#pragma unroll
            for (int r = 0; r < 4; ++r)
                red[wave][i * 16 + (lane >> 4) * 4 + r][j * 16 + (lane & 15)] = acc[i][j][r];
    __syncthreads();
    float* pp = P + ((size_t)(b * HEADS + h) * NCH + s) * HD * HD;
    for (int idx = tid; idx < HD * HD; idx += 128)
        pp[idx] = (&red[0][0][0])[idx] + (&red[1][0][0])[idx];
}

// ---------------- FUSED norms + softmax: grid (HEADS*HD, NB), block 64.
// Each block computes fn_c (lane-split + reduce) and per-lane fn_d from SS,
// then the softmax row — normreduce kernel and Fn buffer deleted.
__global__ void softmax_kernel(const float* __restrict__ SS, const float* __restrict__ P,
                               const float* __restrict__ temp, float* __restrict__ A) {
    const int b = blockIdx.y;
    const int h = blockIdx.x / HD, c = blockIdx.x % HD;
    const float* ssb = SS + ((size_t)(b * HEADS + h) * NCH) * 2 * 96;
    const float* Pb = P + (size_t)b * HEADS * NCH * HD * HD;
    const int d = threadIdx.x;
    // fn_c: 72 partials spread across 64 lanes
    float pc = 0.f;
    for (int u = d; u < NCH * 2; u += 64) pc += ssb[u * 96 + c];
    for (int off = 32; off; off >>= 1) pc += __shfl_xor(pc, off);
    const float fnc = 1.f / fmaxf(sqrtf(pc), 1e-12f);
    // fn_d: per-lane serial sum (coalesced, L2-resident)
    float sd = 0.f;
    if (d < HD)
        for (int u = 0; u < NCH * 2; ++u) sd += ssb[u * 96 + 48 + d];
    const float fnd = 1.f / fmaxf(sqrtf(sd), 1e-12f);
    float val = 0.f, v = -INFINITY;
    if (d < HD) {
        float sum = 0.f;
        for (int s = 0; s < NCH; ++s) sum += Pb[((size_t)(h * NCH + s) * HD + c) * HD + d];
        val = sum * fnc * fnd * temp[h];
        v = val;
    }
    float m = v;
    for (int off = 32; off; off >>= 1) m = fmaxf(m, __shfl_xor(m, off));
    const float e = (d < HD) ? expf(val - m) : 0.f;
    float se = e;
    for (int off = 32; off; off >>= 1) se += __shfl_xor(se, off);
    if (d < HD) A[((size_t)b * HEADS + h) * HD * HD + (size_t)c * HD + d] = e / se;
}

// ---------------- WP_eff[b][o][h*48+d] = sum_c wp[o][h*48+c]*attn[b][h][c][d]
__global__ void wpeff_kernel(const float* __restrict__ Wp, const float* __restrict__ At,
                             _Float16* __restrict__ WPe) {
    const int og = blockIdx.x, h = blockIdx.y, b = blockIdx.z;
    const int o0 = og * 48;
    const int tid = threadIdx.x;
    __shared__ float as2[HD][HD];   // attn[c][d]
    __shared__ float wpb[HD][HD];   // wp[o0+r][h*48+c]
    const float* ab = At + ((size_t)(b * HEADS + h)) * HD * HD;
    for (int wi = tid; wi < HD * HD; wi += 256) {
        (&as2[0][0])[wi] = ab[wi];
        wpb[wi / HD][wi % HD] = Wp[(size_t)(o0 + wi / HD) * DIM + h * HD + wi % HD];
    }
    __syncthreads();
#pragma unroll
    for (int it = 0; it < 3; ++it) {
        const int wi = it * 256 + tid;       // 48o * 12 d-quads = 576
        if (wi >= 576) break;
        const int ol = wi / 12, d0 = (wi % 12) * 4;
        f32x4 acc = {};
#pragma unroll
        for (int c = 0; c < HD; ++c) {
            const float wv = wpb[ol][c];
            const f32x4 a4 = *(const f32x4*)&as2[c][d0];
            acc.x += wv * a4.x; acc.y += wv * a4.y; acc.z += wv * a4.z; acc.w += wv * a4.w;
        }
        f16x4 r;
        r[0] = (_Float16)acc.x; r[1] = (_Float16)acc.y;
        r[2] = (_Float16)acc.z; r[3] = (_Float16)acc.w;
        *(f16x4*)&WPe[((size_t)b * DIM + o0 + ol) * DIM + h * HD + d0] = r;
    }
}

extern "C" void kernel_launch(void* const* d_in, const int* in_sizes, int n_in,
                              void* d_out, int out_size, void* d_ws, size_t ws_size,
                              hipStream_t stream) {
    const float* x      = (const float*)d_in[0];
    const float* w_qkv  = (const float*)d_in[1];
    const float* w_dw   = (const float*)d_in[2];
    const float* w_proj = (const float*)d_in[3];
    const float* temp   = (const float*)d_in[4];
    float* out = (float*)d_out;

    char* ws = (char*)d_ws;
    const size_t SZ_XT  = (size_t)NB * NPIX * DIM * 2;   // 28.3 MB
    const size_t SZ_QKV = (size_t)NB * OC3 * NPIX * 2;   // 84.9 MB
    const size_t SZ_QK  = (size_t)NB * 768 * NPIX * 2;   // 56.6 MB
    const size_t SZ_VT  = SZ_XT;                          // 28.3 MB
    _Float16* XT      = (_Float16*)(ws);
    _Float16* qkv16   = (_Float16*)(ws + SZ_XT);
    _Float16* qkdw16  = (_Float16*)(ws + SZ_XT + SZ_QKV);
    _Float16* vT16    = (_Float16*)(ws + SZ_XT + SZ_QKV + SZ_QK);
    char* tail = ws + SZ_XT + SZ_QKV + SZ_QK + SZ_VT;
    _Float16* W16q = (_Float16*)(tail);                              // 884736 B
    float*    Pp   = (float*)(tail + 1024 * 1024 + 65536);           // 10.6 MB
    float*    At   = (float*)(tail + 12 * 1024 * 1024);              // 294912 B
    float*    SS   = (float*)(tail + 13 * 1024 * 1024);              // 884736 B
    _Float16* WPe  = (_Float16*)(tail + 14 * 1024 * 1024);           // 1.18 MB

    convert_w_kernel<<<(OC3 * DIM / 4 + 255) / 256, 256, 0, stream>>>(w_qkv, W16q, OC3 * DIM / 4);

    convert_xt_kernel<<<dim3(NPIX / 64, DIM / 128, NB), 256, 0, stream>>>(x, XT);
    gemm16_kernel<_Float16><<<dim3(NPIX / 128, OC3 / 128, NB), 256, 0, stream>>>(
        W16q, XT, qkv16, 0, (size_t)NPIX * DIM, (size_t)OC3 * NPIX);
    dwconv_qk_kernel<<<(NB * 768 * 576) / 256, 256, 0, stream>>>(qkv16, w_dw, qkdw16);
    dwconv_vt_kernel<<<dim3(NPIX / 256, HEADS, NB), 256, 0, stream>>>(
        qkv16, w_dw, (unsigned*)vT16);
    gram16_kernel<<<dim3(NCH, HEADS, NB), 128, 0, stream>>>(qkdw16, Pp, SS);
    softmax_kernel<<<dim3(HEADS * HD, NB), 64, 0, stream>>>(SS, Pp, temp, At);
    wpeff_kernel<<<dim3(8, HEADS, NB), 256, 0, stream>>>(w_proj, At, WPe);
    gemm16_kernel<float><<<dim3(NPIX / 128, DIM / 128, NB), 256, 0, stream>>>(
        WPe, vT16, out, (size_t)DIM * DIM, (size_t)NPIX * DIM, (size_t)DIM * NPIX);
}

// Round 20
// 159.886 us; speedup vs baseline: 1.0602x; 1.0406x over previous
//
#include <hip/hip_runtime.h>
#include <hip/hip_bf16.h>
#include <math.h>

#define DIM   384
#define HEADS 8
#define HD    48
#define HH    96
#define WW    96
#define NPIX  9216
#define OC3   1152
#define NCH   36      // gram n-chunks (36*256 = 9216)
#define NB    4

typedef _Float16 f16x8 __attribute__((ext_vector_type(8)));
typedef _Float16 f16x4 __attribute__((ext_vector_type(4)));
typedef _Float16 f16x2 __attribute__((ext_vector_type(2)));
typedef float f32x4 __attribute__((ext_vector_type(4)));

// ---------------- MERGED: x fp32 -> XT f16 (blocks [0,1728)) + W fp32 -> f16 (rest)
__global__ void cvt_all_kernel(const float* __restrict__ x, const float* __restrict__ Wq,
                               _Float16* __restrict__ XT, _Float16* __restrict__ W16) {
    __shared__ _Float16 t[128][66];
    const int blk = blockIdx.x;
    const int tid = threadIdx.x;
    if (blk < 1728) {             // convert_xt: (144, 3, 4) flattened
        const int bx = blk % 144, by = (blk / 144) % 3, b = blk / 432;
        const float* In = x + (size_t)b * DIM * NPIX;
        _Float16* Out = XT + (size_t)b * NPIX * DIM;
        const int n0 = bx * 64, c0 = by * 128;
        const int col = tid & 63, rb = tid >> 6;
#pragma unroll
        for (int i = 0; i < 32; ++i) {
            const int r = i * 4 + rb;
            t[r][col] = (_Float16)In[(size_t)(c0 + r) * NPIX + n0 + col];
        }
        __syncthreads();
#pragma unroll
        for (int i = 0; i < 16; ++i) {
            const int n = i * 4 + rb;
            f16x2 v;
            v[0] = t[col * 2][n];
            v[1] = t[col * 2 + 1][n];
            *(f16x2*)&Out[(size_t)(n0 + n) * DIM + c0 + col * 2] = v;
        }
    } else {                      // convert_w: 432 blocks
        const int i = (blk - 1728) * 256 + tid;
        if (i < OC3 * DIM / 4) {
            const float4 v = reinterpret_cast<const float4*>(Wq)[i];
            _Float16* o = W16 + (size_t)i * 4;
            o[0] = (_Float16)v.x; o[1] = (_Float16)v.y;
            o[2] = (_Float16)v.z; o[3] = (_Float16)v.w;
        }
    }
}

// ---------------- MFMA GEMM (R17 frozen): 128x128, BK=64, dbuf LDS, XOR swizzle,
// XCD-aware bijective block swizzle, LDS-staged vectorized epilogue.
template<typename OutT>
__global__ void gemm16_kernel(const _Float16* __restrict__ A, const _Float16* __restrict__ BT,
                              OutT* __restrict__ Y, size_t astride, size_t bstride, size_t ystride) {
    __shared__ __attribute__((aligned(16))) char smem[65536];  // A:2x16KB | B:2x16KB, reused for C
    const int tid = threadIdx.x;
    const int lane = tid & 63, wid = tid >> 6;
    const int gx = gridDim.x, gy = gridDim.y;
    const int Dl = blockIdx.x + gx * (blockIdx.y + gy * blockIdx.z);
    const int T  = gx * gy * (int)gridDim.z;
    const int S  = (Dl & 7) * (T >> 3) + (Dl >> 3);
    const int m0 = (S % gy) * 128;
    const int rest = S / gy;
    const int n0 = (rest % gx) * 128;
    const int zi = rest / gx;
    A  += (size_t)zi * astride;
    BT += (size_t)zi * bstride;
    Y  += (size_t)zi * ystride;
    const int wrow = (wid >> 1) * 64, wcol = (wid & 1) * 64;

    auto stage = [&](int buf, int t) {
        const int k0 = t * 64;
#pragma unroll
        for (int issue = 0; issue < 4; ++issue) {
            const int p = issue * 4096 + wid * 1024 + lane * 16;   // linear LDS byte pos
            const int row = p >> 7;
            const int cb  = (p & 127) ^ ((row & 7) << 4);          // swizzled source col-bytes
            const int kp  = cb >> 1;
            __builtin_amdgcn_global_load_lds(
                (const __attribute__((address_space(1))) void*)&A[(size_t)(m0 + row) * 384 + k0 + kp],
                (__attribute__((address_space(3))) void*)(smem + buf * 16384 + p), 16, 0, 0);
            __builtin_amdgcn_global_load_lds(
                (const __attribute__((address_space(1))) void*)&BT[(size_t)(n0 + row) * 384 + k0 + kp],
                (__attribute__((address_space(3))) void*)(smem + 32768 + buf * 16384 + p), 16, 0, 0);
        }
    };

    f32x4 acc[4][4] = {};
    stage(0, 0);
    __syncthreads();
    int cur = 0;
    for (int t = 0; t < 6; ++t) {
        if (t + 1 < 6) stage(cur ^ 1, t + 1);   // prefetch overlaps compute below
        const char* Ab = smem + cur * 16384;
        const char* Bb = smem + 32768 + cur * 16384;
#pragma unroll
        for (int ksub = 0; ksub < 2; ++ksub) {
            const int cb = ksub * 64 + (lane >> 4) * 16;   // byte col within row
            f16x8 af[4], bf[4];
#pragma unroll
            for (int mi = 0; mi < 4; ++mi) {
                const int r = wrow + mi * 16 + (lane & 15);
                af[mi] = *(const f16x8*)(Ab + r * 128 + (cb ^ ((r & 7) << 4)));
            }
#pragma unroll
            for (int ni = 0; ni < 4; ++ni) {
                const int r = wcol + ni * 16 + (lane & 15);
                bf[ni] = *(const f16x8*)(Bb + r * 128 + (cb ^ ((r & 7) << 4)));
            }
#pragma unroll
            for (int mi = 0; mi < 4; ++mi)
#pragma unroll
                for (int ni = 0; ni < 4; ++ni)
                    acc[mi][ni] = __builtin_amdgcn_mfma_f32_16x16x32_f16(af[mi], bf[ni], acc[mi][ni], 0, 0, 0);
        }
        __syncthreads();
        cur ^= 1;
    }
    // --- epilogue: C tile -> swizzled LDS -> coalesced 16B stores
    constexpr int EB = (int)sizeof(OutT);         // 2 or 4
    constexpr int ROWB = 128 * EB;                // LDS bytes per C row
#pragma unroll
    for (int mi = 0; mi < 4; ++mi)
#pragma unroll
        for (int ni = 0; ni < 4; ++ni) {
            const int col = wcol + ni * 16 + (lane & 15);
#pragma unroll
            for (int r = 0; r < 4; ++r) {
                const int row = wrow + mi * 16 + (lane >> 4) * 4 + r;
                *(OutT*)(smem + row * ROWB + ((col * EB) ^ ((row & 7) << 4))) = (OutT)acc[mi][ni][r];
            }
        }
    __syncthreads();
    constexpr int CPR = ROWB / 16;                // 16B chunks per row (16 or 32)
    constexpr int ITER = 128 * CPR / 256;         // 8 or 16
#pragma unroll
    for (int i = 0; i < ITER; ++i) {
        const int idx = i * 256 + tid;
        const int row = idx / CPR, ch = idx % CPR;
        *(uint4*)&Y[(size_t)(m0 + row) * NPIX + n0 + ch * (16 / EB)] =
            *(const uint4*)(smem + row * ROWB + ((ch * 16) ^ ((row & 7) << 4)));
    }
}

// ---------------- MERGED depthwise 3x3: qk blocks [0, 6912) write [b][768][NPIX];
// vt blocks [6912, 8064) fuse v-dwconv with transposed vT[b][n][384] write.
#define QKBLK 6912
__global__ void dwconv_all_kernel(const _Float16* __restrict__ In, const float* __restrict__ Wd,
                                  _Float16* __restrict__ OutQK, unsigned* __restrict__ OutVT) {
    __shared__ _Float16 tt[48][264];   // used by vt branch only
    const int tid = threadIdx.x, lane = tid & 63;
    if (blockIdx.x < QKBLK) {
        // ---- qk: 16 px/thread, 1 output row, halos via shuffle (R17-proven)
        const int idx = blockIdx.x * 256 + tid;            // over NB*768*576
        const int ci = idx / 576;
        const int p0 = (idx - ci * 576) * 16;
        const int b = ci / 768, c = ci % 768;
        const _Float16* ip = In + ((size_t)b * OC3 + c) * NPIX;
        const float* w = &Wd[c * 9];
        const int y = p0 / WW, x0 = p0 % WW;
        float o[16] = {};
#pragma unroll
        for (int dy = -1; dy <= 1; ++dy) {
            const int yy = y + dy;
            if (yy < 0 || yy >= HH) continue;
            const _Float16* row = ip + yy * WW;
            const f16x8 m0 = *(const f16x8*)&row[x0];
            const f16x8 m1 = *(const f16x8*)&row[x0 + 8];
            float v[18];
#pragma unroll
            for (int j = 0; j < 8; ++j) { v[j + 1] = (float)m0[j]; v[j + 9] = (float)m1[j]; }
            float left  = __shfl_up(v[16], 1);
            float right = __shfl_down(v[1], 1);
            if (lane == 0  && x0 > 0)        left  = (float)row[x0 - 1];
            if (lane == 63 && x0 + 16 < WW)  right = (float)row[x0 + 16];
            v[0]  = (x0 > 0)       ? left  : 0.f;
            v[17] = (x0 + 16 < WW) ? right : 0.f;
            const float w0 = w[(dy + 1) * 3], w1 = w[(dy + 1) * 3 + 1], w2 = w[(dy + 1) * 3 + 2];
#pragma unroll
            for (int j = 0; j < 16; ++j) o[j] += w0 * v[j] + w1 * v[j + 1] + w2 * v[j + 2];
        }
        f16x8 r0, r1;
#pragma unroll
        for (int j = 0; j < 8; ++j) { r0[j] = (_Float16)o[j]; r1[j] = (_Float16)o[j + 8]; }
        *(f16x8*)&OutQK[(size_t)ci * NPIX + p0] = r0;
        *(f16x8*)&OutQK[(size_t)ci * NPIX + p0 + 8] = r1;
    } else {
        // ---- vt: 256-px tiles, 16 px/thread, LDS transpose write
        const int flat = blockIdx.x - QKBLK;               // < 1152
        const int pt = flat % 36, rest = flat / 36;
        const int h = rest % HEADS, b = rest / HEADS;
        const int n0 = pt * 256;
        const int px0 = (tid & 15) * 16;
        const int cg = tid >> 4;
        const int p0 = n0 + px0;
        const int y = p0 / WW, x0 = p0 % WW;
#pragma unroll
        for (int i = 0; i < 3; ++i) {
            const int c = cg * 3 + i;
            const _Float16* ip = In + ((size_t)b * OC3 + 2 * DIM + h * HD + c) * NPIX;
            const float* w = &Wd[(2 * DIM + h * HD + c) * 9];
            float o[16] = {};
#pragma unroll
            for (int dy = -1; dy <= 1; ++dy) {
                const int yy = y + dy;
                if (yy < 0 || yy >= HH) continue;
                const _Float16* row = ip + yy * WW;
                const f16x8 m0 = *(const f16x8*)&row[x0];
                const f16x8 m1 = *(const f16x8*)&row[x0 + 8];
                float v[18];
#pragma unroll
                for (int j = 0; j < 8; ++j) { v[j + 1] = (float)m0[j]; v[j + 9] = (float)m1[j]; }
                float left  = __shfl_up(v[16], 1);
                float right = __shfl_down(v[1], 1);
                if ((lane & 15) == 0  && x0 > 0)        left  = (float)row[x0 - 1];
                if ((lane & 15) == 15 && x0 + 16 < WW)  right = (float)row[x0 + 16];
                v[0]  = (x0 > 0)       ? left  : 0.f;
                v[17] = (x0 + 16 < WW) ? right : 0.f;
                const float w0 = w[(dy + 1) * 3], w1 = w[(dy + 1) * 3 + 1], w2 = w[(dy + 1) * 3 + 2];
#pragma unroll
                for (int j = 0; j < 16; ++j) o[j] += w0 * v[j] + w1 * v[j + 1] + w2 * v[j + 2];
            }
            f16x8 r0, r1;
#pragma unroll
            for (int j = 0; j < 8; ++j) { r0[j] = (_Float16)o[j]; r1[j] = (_Float16)o[j + 8]; }
            *(f16x8*)&tt[c][px0] = r0;
            *(f16x8*)&tt[c][px0 + 8] = r1;
        }
        __syncthreads();
#pragma unroll
        for (int it = 0; it < 24; ++it) {
            const int i = it * 256 + tid;          // < 6144
            const int r = i / 24, c2 = i % 24;
            union { _Float16 hh[2]; unsigned u; } pk;
            pk.hh[0] = tt[2 * c2][r];
            pk.hh[1] = tt[2 * c2 + 1][r];
            OutVT[((size_t)b * NPIX + n0 + r) * 192 + h * 24 + c2] = pk.u;
        }
    }
}

// ---------------- MFMA gram; sumsq ALSO via MFMA (diag of q.q^T / k.k^T)
__global__ void gram16_kernel(const _Float16* __restrict__ QK, float* __restrict__ P,
                              float* __restrict__ SS) {
    const int h = blockIdx.y, s = blockIdx.x, b = blockIdx.z;
    QK += (size_t)b * 768 * NPIX;
    const int tid = threadIdx.x;
    const int lane = tid & 63, wave = tid >> 6;
    const _Float16* q = QK + (size_t)(h * HD) * NPIX;
    const _Float16* k = QK + (size_t)(DIM + h * HD) * NPIX;
    const int rowa = lane & 15, koff = (lane >> 4) * 8;
    f32x4 acc[3][3] = {};
    f32x4 aqq[3] = {}, akk[3] = {};
#pragma unroll
    for (int kk = 0; kk < 4; ++kk) {
        const int nk = s * 256 + wave * 128 + kk * 32 + koff;
        f16x8 aq[3], bk[3];
#pragma unroll
        for (int i = 0; i < 3; ++i)
            aq[i] = *(const f16x8*)&q[(size_t)(i * 16 + rowa) * NPIX + nk];
#pragma unroll
        for (int j = 0; j < 3; ++j)
            bk[j] = *(const f16x8*)&k[(size_t)(j * 16 + rowa) * NPIX + nk];
#pragma unroll
        for (int i = 0; i < 3; ++i) {
            aqq[i] = __builtin_amdgcn_mfma_f32_16x16x32_f16(aq[i], aq[i], aqq[i], 0, 0, 0);
            akk[i] = __builtin_amdgcn_mfma_f32_16x16x32_f16(bk[i], bk[i], akk[i], 0, 0, 0);
        }
#pragma unroll
        for (int i = 0; i < 3; ++i)
#pragma unroll
            for (int j = 0; j < 3; ++j)
                acc[i][j] = __builtin_amdgcn_mfma_f32_16x16x32_f16(aq[i], bk[j], acc[i][j], 0, 0, 0);
    }
    // diag of q.q^T: row==col=c lives at lane = c + 16*(c>>2), reg r = c&3
    const int cd = lane & 15;
    if ((lane >> 4) == (cd >> 2)) {
        float* ssb = SS + (((size_t)(b * HEADS + h) * NCH + s) * 2 + wave) * 96;
#pragma unroll
        for (int i = 0; i < 3; ++i) {
            ssb[i * 16 + cd]      = aqq[i][cd & 3];
            ssb[48 + i * 16 + cd] = akk[i][cd & 3];
        }
    }
    __shared__ float red[2][HD][HD];
#pragma unroll
    for (int i = 0; i < 3; ++i)
#pragma unroll
        for (int j = 0; j < 3; ++j)
#pragma unroll
            for (int r = 0; r < 4; ++r)
                red[wave][i * 16 + (lane >> 4) * 4 + r][j * 16 + (lane & 15)] = acc[i][j][r];
    __syncthreads();
    float* pp = P + ((size_t)(b * HEADS + h) * NCH + s) * HD * HD;
    for (int idx = tid; idx < HD * HD; idx += 128)
        pp[idx] = (&red[0][0][0])[idx] + (&red[1][0][0])[idx];
}

// ---------------- FUSED norms + softmax: grid (HEADS*HD, NB), block 64.
__global__ void softmax_kernel(const float* __restrict__ SS, const float* __restrict__ P,
                               const float* __restrict__ temp, float* __restrict__ A) {
    const int b = blockIdx.y;
    const int h = blockIdx.x / HD, c = blockIdx.x % HD;
    const float* ssb = SS + ((size_t)(b * HEADS + h) * NCH) * 2 * 96;
    const float* Pb = P + (size_t)b * HEADS * NCH * HD * HD;
    const int d = threadIdx.x;
    float pc = 0.f;
    for (int u = d; u < NCH * 2; u += 64) pc += ssb[u * 96 + c];
    for (int off = 32; off; off >>= 1) pc += __shfl_xor(pc, off);
    const float fnc = 1.f / fmaxf(sqrtf(pc), 1e-12f);
    float sd = 0.f;
    if (d < HD)
        for (int u = 0; u < NCH * 2; ++u) sd += ssb[u * 96 + 48 + d];
    const float fnd = 1.f / fmaxf(sqrtf(sd), 1e-12f);
    float val = 0.f, v = -INFINITY;
    if (d < HD) {
        float sum = 0.f;
        for (int s = 0; s < NCH; ++s) sum += Pb[((size_t)(h * NCH + s) * HD + c) * HD + d];
        val = sum * fnc * fnd * temp[h];
        v = val;
    }
    float m = v;
    for (int off = 32; off; off >>= 1) m = fmaxf(m, __shfl_xor(m, off));
    const float e = (d < HD) ? expf(val - m) : 0.f;
    float se = e;
    for (int off = 32; off; off >>= 1) se += __shfl_xor(se, off);
    if (d < HD) A[((size_t)b * HEADS + h) * HD * HD + (size_t)c * HD + d] = e / se;
}

// ---------------- WP_eff[b][o][h*48+d] = sum_c wp[o][h*48+c]*attn[b][h][c][d]
__global__ void wpeff_kernel(const float* __restrict__ Wp, const float* __restrict__ At,
                             _Float16* __restrict__ WPe) {
    const int og = blockIdx.x, h = blockIdx.y, b = blockIdx.z;
    const int o0 = og * 48;
    const int tid = threadIdx.x;
    __shared__ float as2[HD][HD];   // attn[c][d]
    __shared__ float wpb[HD][HD];   // wp[o0+r][h*48+c]
    const float* ab = At + ((size_t)(b * HEADS + h)) * HD * HD;
    for (int wi = tid; wi < HD * HD; wi += 256) {
        (&as2[0][0])[wi] = ab[wi];
        wpb[wi / HD][wi % HD] = Wp[(size_t)(o0 + wi / HD) * DIM + h * HD + wi % HD];
    }
    __syncthreads();
#pragma unroll
    for (int it = 0; it < 3; ++it) {
        const int wi = it * 256 + tid;       // 48o * 12 d-quads = 576
        if (wi >= 576) break;
        const int ol = wi / 12, d0 = (wi % 12) * 4;
        f32x4 acc = {};
#pragma unroll
        for (int c = 0; c < HD; ++c) {
            const float wv = wpb[ol][c];
            const f32x4 a4 = *(const f32x4*)&as2[c][d0];
            acc.x += wv * a4.x; acc.y += wv * a4.y; acc.z += wv * a4.z; acc.w += wv * a4.w;
        }
        f16x4 r;
        r[0] = (_Float16)acc.x; r[1] = (_Float16)acc.y;
        r[2] = (_Float16)acc.z; r[3] = (_Float16)acc.w;
        *(f16x4*)&WPe[((size_t)b * DIM + o0 + ol) * DIM + h * HD + d0] = r;
    }
}

extern "C" void kernel_launch(void* const* d_in, const int* in_sizes, int n_in,
                              void* d_out, int out_size, void* d_ws, size_t ws_size,
                              hipStream_t stream) {
    const float* x      = (const float*)d_in[0];
    const float* w_qkv  = (const float*)d_in[1];
    const float* w_dw   = (const float*)d_in[2];
    const float* w_proj = (const float*)d_in[3];
    const float* temp   = (const float*)d_in[4];
    float* out = (float*)d_out;

    char* ws = (char*)d_ws;
    const size_t SZ_XT  = (size_t)NB * NPIX * DIM * 2;   // 28.3 MB
    const size_t SZ_QKV = (size_t)NB * OC3 * NPIX * 2;   // 84.9 MB
    const size_t SZ_QK  = (size_t)NB * 768 * NPIX * 2;   // 56.6 MB
    const size_t SZ_VT  = SZ_XT;                          // 28.3 MB
    _Float16* XT      = (_Float16*)(ws);
    _Float16* qkv16   = (_Float16*)(ws + SZ_XT);
    _Float16* qkdw16  = (_Float16*)(ws + SZ_XT + SZ_QKV);
    _Float16* vT16    = (_Float16*)(ws + SZ_XT + SZ_QKV + SZ_QK);
    char* tail = ws + SZ_XT + SZ_QKV + SZ_QK + SZ_VT;
    _Float16* W16q = (_Float16*)(tail);                              // 884736 B
    float*    Pp   = (float*)(tail + 1024 * 1024 + 65536);           // 10.6 MB
    float*    At   = (float*)(tail + 12 * 1024 * 1024);              // 294912 B
    float*    SS   = (float*)(tail + 13 * 1024 * 1024);              // 884736 B
    _Float16* WPe  = (_Float16*)(tail + 14 * 1024 * 1024);           // 1.18 MB

    cvt_all_kernel<<<1728 + 432, 256, 0, stream>>>(x, w_qkv, XT, W16q);
    gemm16_kernel<_Float16><<<dim3(NPIX / 128, OC3 / 128, NB), 256, 0, stream>>>(
        W16q, XT, qkv16, 0, (size_t)NPIX * DIM, (size_t)OC3 * NPIX);
    dwconv_all_kernel<<<QKBLK + NB * HEADS * 36, 256, 0, stream>>>(
        qkv16, w_dw, qkdw16, (unsigned*)vT16);
    gram16_kernel<<<dim3(NCH, HEADS, NB), 128, 0, stream>>>(qkdw16, Pp, SS);
    softmax_kernel<<<dim3(HEADS * HD, NB), 64, 0, stream>>>(SS, Pp, temp, At);
    wpeff_kernel<<<dim3(8, HEADS, NB), 256, 0, stream>>>(w_proj, At, WPe);
    gemm16_kernel<float><<<dim3(NPIX / 128, DIM / 128, NB), 256, 0, stream>>>(
        WPe, vT16, out, (size_t)DIM * DIM, (size_t)NPIX * DIM, (size_t)DIM * NPIX);
}